// Round 1
// baseline (627.341 us; speedup 1.0000x reference)
//
#include <hip/hip_runtime.h>

typedef short short8 __attribute__((ext_vector_type(8)));
typedef float f32x4 __attribute__((ext_vector_type(4)));
typedef unsigned short ushort;

#define MFMA(a, b, c) __builtin_amdgcn_mfma_f32_16x16x32_bf16(a, b, c, 0, 0, 0)

// ---- ws layout (ushort/bf16 element offsets) ----
#define WS_WQT 0        // [96][96]   (out, in) K-contig
#define WS_WKT 9216     // [96][192]
#define WS_WVT 27648    // [96][192]
#define WS_WOT 46080    // [96][96]
#define WS_TOTAL 55296

// ---- LDS layout (byte offsets) ----
#define STR_A 104           // bf16 row stride for [64][96] tiles (208B rows, 16B aligned, 2-way banks)
#define OFF_A 0             // 13312 B : A_q / A_kv half / p_scratch / o_buf (phased reuse)
#define OFF_Q16 13312       // [6][64][16] bf16 = 12288
#define OFF_K16 25600       // [6][64][16] bf16 = 12288
#define OFF_VT 37888        // [6][16][72] bf16 = 13824 (token-contig, padded)
#define STR_VT 72
#define OFF_BIAS 51712      // [225*6] f32 = 5400
#define LDS_BYTES 57112
#define P_STRIDE 72         // p_scratch row stride (bf16)

__device__ __forceinline__ ushort f2bf(float x) {
    unsigned u = __float_as_uint(x);
    u = (u + 0x7FFFu + ((u >> 16) & 1u)) >> 16;   // RNE
    return (ushort)u;
}

__global__ void prep_weights(const float* __restrict__ Wq, const float* __restrict__ Wk,
                             const float* __restrict__ Wv, const float* __restrict__ Wo,
                             ushort* __restrict__ ws) {
    int idx = blockIdx.x * 256 + threadIdx.x;
    if (idx < 9216) {                       // WqT[o][i] = Wq[i][o]
        int o = idx / 96, i = idx % 96;
        ws[WS_WQT + idx] = f2bf(Wq[i * 96 + o]);
    } else if (idx < 27648) {               // WkT[o][i] = Wk[i][o], [96][192]
        int t = idx - 9216; int o = t / 192, i = t % 192;
        ws[idx] = f2bf(Wk[i * 96 + o]);
    } else if (idx < 46080) {               // WvT
        int t = idx - 27648; int o = t / 192, i = t % 192;
        ws[idx] = f2bf(Wv[i * 96 + o]);
    } else if (idx < 55296) {               // WoT[o][i] = Wo[i][o]
        int t = idx - 46080; int o = t / 96, i = t % 96;
        ws[idx] = f2bf(Wo[i * 96 + o]);
    }
}

__global__ __launch_bounds__(256, 2) void swin_attn(
    const float* __restrict__ xq, const float* __restrict__ xkv,
    const float* __restrict__ bq, const float* __restrict__ bk,
    const float* __restrict__ bv, const float* __restrict__ btab,
    const float* __restrict__ bo, const ushort* __restrict__ ws,
    float* __restrict__ out)
{
    __shared__ __align__(16) char smem[LDS_BYTES];
    const int tid = threadIdx.x;
    const int wave = tid >> 6, lane = tid & 63;
    const int l15 = lane & 15, quad = lane >> 4;
    // XCD swizzle: blocks resident on one XCD handle w-adjacent windows (share 128B lines)
    int wid = ((blockIdx.x & 7) << 9) | (blockIdx.x >> 3);
    const int b = wid >> 10;
    const int wh = (wid >> 5) & 31, ww = wid & 31;
    const int h0 = wh * 8, w0 = ww * 8;
    const int mt = wave;                     // each wave owns one 16-token M-tile

    ushort* A    = (ushort*)(smem + OFF_A);
    ushort* q16  = (ushort*)(smem + OFF_Q16);
    ushort* k16  = (ushort*)(smem + OFF_K16);
    ushort* vt   = (ushort*)(smem + OFF_VT);
    float*  biasl = (float*)(smem + OFF_BIAS);

    // ---- stage bias table + A_q window tile [64 tok][96 ch] bf16 ----
    for (int i = tid; i < 1350; i += 256) biasl[i] = btab[i];
    const float* xqb = xq + (size_t)b * 96 * 65536;
    for (int p = tid; p < 768; p += 256) {
        int c = p % 96, i = p / 96;
        const float* g = xqb + (size_t)c * 65536 + (h0 + i) * 256 + w0;
        float4 f0 = *(const float4*)g, f1 = *(const float4*)(g + 4);
        int base = (i * 8) * STR_A + c;
        A[base]             = f2bf(f0.x); A[base + STR_A]     = f2bf(f0.y);
        A[base + 2 * STR_A] = f2bf(f0.z); A[base + 3 * STR_A] = f2bf(f0.w);
        A[base + 4 * STR_A] = f2bf(f1.x); A[base + 5 * STR_A] = f2bf(f1.y);
        A[base + 6 * STR_A] = f2bf(f1.z); A[base + 7 * STR_A] = f2bf(f1.w);
    }
    __syncthreads();

    // ---- q projection: q16[h][tok][d] = (A_q @ Wq + bq) * 0.25 (scale=hd^-.5=2^-2 exact) ----
    {
        const int arow = (mt * 16 + l15) * STR_A + quad * 8;
        for (int nt = 0; nt < 6; ++nt) {
            f32x4 acc = {};
            #pragma unroll
            for (int kt = 0; kt < 3; ++kt) {
                short8 a  = *(const short8*)(A + arow + kt * 32);
                short8 bb = *(const short8*)(ws + WS_WQT + (nt * 16 + l15) * 96 + kt * 32 + quad * 8);
                acc = MFMA(a, bb, acc);
            }
            float bias = bq[nt * 16 + l15];
            ushort* dst = q16 + nt * (64 * 16) + (mt * 16 + quad * 4) * 16 + l15;
            #pragma unroll
            for (int r = 0; r < 4; ++r) dst[r * 16] = f2bf((acc[r] + bias) * 0.25f);
        }
    }
    __syncthreads();

    // ---- k/v projections: stage kv in two 96-channel halves, accumulate in regs ----
    f32x4 accK[6], accV[6];
    #pragma unroll
    for (int n = 0; n < 6; ++n) { accK[n] = {}; accV[n] = {}; }
    const float* xkvb = xkv + (size_t)b * 192 * 65536;
    for (int half = 0; half < 2; ++half) {
        for (int p = tid; p < 768; p += 256) {
            int c = p % 96, i = p / 96;
            const float* g = xkvb + (size_t)(half * 96 + c) * 65536 + (h0 + i) * 256 + w0;
            float4 f0 = *(const float4*)g, f1 = *(const float4*)(g + 4);
            int base = (i * 8) * STR_A + c;
            A[base]             = f2bf(f0.x); A[base + STR_A]     = f2bf(f0.y);
            A[base + 2 * STR_A] = f2bf(f0.z); A[base + 3 * STR_A] = f2bf(f0.w);
            A[base + 4 * STR_A] = f2bf(f1.x); A[base + 5 * STR_A] = f2bf(f1.y);
            A[base + 6 * STR_A] = f2bf(f1.z); A[base + 7 * STR_A] = f2bf(f1.w);
        }
        __syncthreads();
        const int arow = (mt * 16 + l15) * STR_A + quad * 8;
        for (int kt = 0; kt < 3; ++kt) {
            short8 a = *(const short8*)(A + arow + kt * 32);
            int koff = half * 96 + kt * 32 + quad * 8;
            #pragma unroll
            for (int nt = 0; nt < 6; ++nt) {
                short8 bk8 = *(const short8*)(ws + WS_WKT + (nt * 16 + l15) * 192 + koff);
                accK[nt] = MFMA(a, bk8, accK[nt]);
                short8 bv8 = *(const short8*)(ws + WS_WVT + (nt * 16 + l15) * 192 + koff);
                accV[nt] = MFMA(a, bv8, accV[nt]);
            }
        }
        __syncthreads();   // A half dead before restage
    }
    #pragma unroll
    for (int nt = 0; nt < 6; ++nt) {
        float bkv = bk[nt * 16 + l15], bvv = bv[nt * 16 + l15];
        ushort* dk = k16 + nt * (64 * 16) + (mt * 16 + quad * 4) * 16 + l15;
        ushort* dv = vt + nt * (16 * STR_VT) + l15 * STR_VT + (mt * 16 + quad * 4);
        #pragma unroll
        for (int r = 0; r < 4; ++r) {
            dk[r * 16] = f2bf(accK[nt][r] + bkv);   // k16[h][tok][d]
            dv[r]      = f2bf(accV[nt][r] + bvv);   // vt[h][d][tok]
        }
    }
    __syncthreads();

    // ---- per-head: S = q k^T (+relbias) -> softmax (in-register) -> P v ----
    f32x4 accO[6];
    const int qtok0 = mt * 16 + quad * 4;
    short8 zero8 = {};
    ushort* ps = (ushort*)(smem + OFF_A) + wave * (16 * P_STRIDE);  // wave-private
    for (int h = 0; h < 6; ++h) {
        short8 aq = zero8;
        if (quad < 2) aq = *(const short8*)(q16 + h * (64 * 16) + (mt * 16 + l15) * 16 + quad * 8);
        f32x4 s[4];
        #pragma unroll
        for (int nt = 0; nt < 4; ++nt) {
            short8 bk8 = zero8;
            if (quad < 2) bk8 = *(const short8*)(k16 + h * (64 * 16) + (nt * 16 + l15) * 16 + quad * 8);
            f32x4 z = {};
            s[nt] = MFMA(aq, bk8, z);
        }
        // relative position bias: idx = (i1-i2+7)*15 + (j1-j2+7)
        #pragma unroll
        for (int nt = 0; nt < 4; ++nt) {
            int kt2 = nt * 16 + l15;
            int i2 = kt2 >> 3, j2 = kt2 & 7;
            #pragma unroll
            for (int r = 0; r < 4; ++r) {
                int qt = qtok0 + r;
                int i1 = qt >> 3, j1 = qt & 7;
                int idx = (i1 - i2 + 7) * 15 + (j1 - j2 + 7);
                s[nt][r] += biasl[idx * 6 + h];
            }
        }
        // row softmax: row lives in 16 lanes of this quad group (xor 1,2,4,8)
        float pr[4][4];
        #pragma unroll
        for (int r = 0; r < 4; ++r) {
            float m = fmaxf(fmaxf(s[0][r], s[1][r]), fmaxf(s[2][r], s[3][r]));
            m = fmaxf(m, __shfl_xor(m, 1)); m = fmaxf(m, __shfl_xor(m, 2));
            m = fmaxf(m, __shfl_xor(m, 4)); m = fmaxf(m, __shfl_xor(m, 8));
            float l = 0.f;
            #pragma unroll
            for (int nt = 0; nt < 4; ++nt) { pr[nt][r] = __expf(s[nt][r] - m); l += pr[nt][r]; }
            l += __shfl_xor(l, 1); l += __shfl_xor(l, 2);
            l += __shfl_xor(l, 4); l += __shfl_xor(l, 8);
            float inv = 1.0f / l;
            #pragma unroll
            for (int nt = 0; nt < 4; ++nt) pr[nt][r] *= inv;
        }
        // C-layout -> A-layout via wave-private LDS slice (in-order within wave)
        #pragma unroll
        for (int nt = 0; nt < 4; ++nt)
            #pragma unroll
            for (int r = 0; r < 4; ++r)
                ps[(quad * 4 + r) * P_STRIDE + nt * 16 + l15] = f2bf(pr[nt][r]);
        f32x4 o = {};
        #pragma unroll
        for (int k2 = 0; k2 < 2; ++k2) {
            short8 ap  = *(const short8*)(ps + l15 * P_STRIDE + k2 * 32 + quad * 8);
            short8 bv8 = *(const short8*)(vt + h * (16 * STR_VT) + l15 * STR_VT + k2 * 32 + quad * 8);
            o = MFMA(ap, bv8, o);
        }
        accO[h] = o;
    }
    __syncthreads();   // all p_scratch reads done before o_buf aliases region A

    // ---- concat heads into o_buf[64][96] ----
    ushort* obuf = (ushort*)(smem + OFF_A);
    #pragma unroll
    for (int h = 0; h < 6; ++h)
        #pragma unroll
        for (int r = 0; r < 4; ++r)
            obuf[(mt * 16 + quad * 4 + r) * STR_A + h * 16 + l15] = f2bf(accO[h][r]);
    __syncthreads();

    // ---- out projection + float4 store to [B,C,H,W] ----
    {
        const int arow = (mt * 16 + l15) * STR_A + quad * 8;
        int t0 = mt * 16 + quad * 4;
        int i = t0 >> 3, j0 = t0 & 7;        // 4 consecutive tokens = 4 consecutive w, same row
        for (int nt = 0; nt < 6; ++nt) {
            f32x4 acc = {};
            #pragma unroll
            for (int kt = 0; kt < 3; ++kt) {
                short8 a  = *(const short8*)(obuf + arow + kt * 32);
                short8 bb = *(const short8*)(ws + WS_WOT + (nt * 16 + l15) * 96 + kt * 32 + quad * 8);
                acc = MFMA(a, bb, acc);
            }
            int cout = nt * 16 + l15;
            float bov = bo[cout];
            float4 v4 = make_float4(acc[0] + bov, acc[1] + bov, acc[2] + bov, acc[3] + bov);
            float* dst = out + (size_t)(b * 96 + cout) * 65536 + (h0 + i) * 256 + w0 + j0;
            *(float4*)dst = v4;
        }
    }
}

extern "C" void kernel_launch(void* const* d_in, const int* in_sizes, int n_in,
                              void* d_out, int out_size, void* d_ws, size_t ws_size,
                              hipStream_t stream) {
    const float* xq   = (const float*)d_in[0];
    const float* xkv  = (const float*)d_in[1];
    const float* Wq   = (const float*)d_in[2];
    const float* bq   = (const float*)d_in[3];
    const float* Wk   = (const float*)d_in[4];
    const float* bk   = (const float*)d_in[5];
    const float* Wv   = (const float*)d_in[6];
    const float* bv   = (const float*)d_in[7];
    const float* btab = (const float*)d_in[8];
    const float* Wo   = (const float*)d_in[9];
    const float* bo   = (const float*)d_in[10];
    ushort* ws = (ushort*)d_ws;
    float* out = (float*)d_out;

    hipLaunchKernelGGL(prep_weights, dim3((WS_TOTAL + 255) / 256), dim3(256), 0, stream,
                       Wq, Wk, Wv, Wo, ws);
    hipLaunchKernelGGL(swin_attn, dim3(4096), dim3(256), 0, stream,
                       xq, xkv, bq, bk, bv, btab, bo, ws, out);
}

// Round 2
// 513.629 us; speedup vs baseline: 1.2214x; 1.2214x over previous
//
#include <hip/hip_runtime.h>

typedef short short8 __attribute__((ext_vector_type(8)));
typedef float f32x4 __attribute__((ext_vector_type(4)));
typedef unsigned short ushort;

#define MFMA(a, b, c) __builtin_amdgcn_mfma_f32_16x16x32_bf16(a, b, c, 0, 0, 0)

// ---- ws layout (ushort element offsets) ----
// Weights are FRAGMENT-PACKED: element j of lane L of fragment f lives at
// base + (f*64 + L)*8 + j  -> each B-frag load is one coalesced 1KB wave txn.
#define WS_WQT 0        // 18 frags (nt*3+kt)          = 9216
#define WS_WKT 9216     // 36 frags (kt6*6+nt)         = 18432
#define WS_WVT 27648    // 36 frags (kt6*6+nt)         = 18432
#define WS_WOT 46080    // 18 frags (nt*3+kt)          = 9216
#define WS_BIAS 55296   // bias table bf16 [225*6]     = 1350
#define WS_TOTAL 56646

// ---- LDS layout (byte offsets), total 53392 B -> 3 blocks/CU ----
#define STR_A 104           // [64][96] tile rows, 208B stride (16B aligned, conflict-spread)
#define OFF_A 0             // 13312 B : A_kv halves -> A_q -> obuf (phased)
#define OFF_K16 13312       // [6][64][16] bf16 = 12288
#define OFF_VT 25600        // [6][16][72] bf16 = 13824 (token-contig)
#define STR_VT 72
#define OFF_PQ 39424        // p_scratch [4][16][72] = 9216 B ; q_scratch @+9216 [4][16][16] = 2048 B
#define P_STRIDE 72
#define OFF_BIAS 50688      // [1350] bf16 = 2700
#define LDS_BYTES 53392

__device__ __forceinline__ ushort f2bf(float x) {
    unsigned u = __float_as_uint(x);
    u = (u + 0x7FFFu + ((u >> 16) & 1u)) >> 16;   // RNE
    return (ushort)u;
}
__device__ __forceinline__ float bf2f(ushort u) {
    return __uint_as_float(((unsigned)u) << 16);
}

__global__ void prep_weights(const float* __restrict__ Wq, const float* __restrict__ Wk,
                             const float* __restrict__ Wv, const float* __restrict__ Wo,
                             const float* __restrict__ btab, ushort* __restrict__ ws) {
    int idx = blockIdx.x * 256 + threadIdx.x;
    if (idx < WS_WKT) {                         // WqT packed, frag = nt*3+kt
        int f = idx >> 9, w = idx & 511, lane = w >> 3, j = w & 7;
        int nt = f / 3, kt = f % 3;
        int n = nt * 16 + (lane & 15), k = kt * 32 + (lane >> 4) * 8 + j;
        ws[idx] = f2bf(Wq[k * 96 + n]);
    } else if (idx < WS_WVT) {                  // WkT packed, frag = kt6*6+nt
        int t = idx - WS_WKT;
        int f = t >> 9, w = t & 511, lane = w >> 3, j = w & 7;
        int kt6 = f / 6, nt = f % 6;
        int n = nt * 16 + (lane & 15), k = kt6 * 32 + (lane >> 4) * 8 + j;
        ws[idx] = f2bf(Wk[k * 96 + n]);
    } else if (idx < WS_WOT) {                  // WvT packed, frag = kt6*6+nt
        int t = idx - WS_WVT;
        int f = t >> 9, w = t & 511, lane = w >> 3, j = w & 7;
        int kt6 = f / 6, nt = f % 6;
        int n = nt * 16 + (lane & 15), k = kt6 * 32 + (lane >> 4) * 8 + j;
        ws[idx] = f2bf(Wv[k * 96 + n]);
    } else if (idx < WS_BIAS) {                 // WoT packed, frag = nt*3+kt
        int t = idx - WS_WOT;
        int f = t >> 9, w = t & 511, lane = w >> 3, j = w & 7;
        int nt = f / 3, kt = f % 3;
        int n = nt * 16 + (lane & 15), k = kt * 32 + (lane >> 4) * 8 + j;
        ws[idx] = f2bf(Wo[k * 96 + n]);
    } else if (idx < WS_TOTAL) {                // bias table -> bf16
        ws[idx] = f2bf(btab[idx - WS_BIAS]);
    }
}

__global__ __launch_bounds__(256, 3) void swin_attn(
    const float* __restrict__ xq, const float* __restrict__ xkv,
    const float* __restrict__ bq, const float* __restrict__ bk,
    const float* __restrict__ bv, const float* __restrict__ bo,
    const ushort* __restrict__ ws, float* __restrict__ out)
{
    __shared__ __align__(16) char smem[LDS_BYTES];
    const int tid = threadIdx.x;
    const int wave = tid >> 6, lane = tid & 63;
    const int l15 = lane & 15, quad = lane >> 4;
    int wid = ((blockIdx.x & 7) << 9) | (blockIdx.x >> 3);   // XCD swizzle: w-adjacent windows co-resident
    const int b = wid >> 10;
    const int wh = (wid >> 5) & 31, ww = wid & 31;
    const int h0 = wh * 8, w0 = ww * 8;
    const int mt = wave;                     // each wave owns one 16-token M-tile

    ushort* A     = (ushort*)(smem + OFF_A);
    ushort* k16   = (ushort*)(smem + OFF_K16);
    ushort* vt    = (ushort*)(smem + OFF_VT);
    ushort* ps    = (ushort*)(smem + OFF_PQ) + wave * (16 * P_STRIDE);  // wave-private P
    ushort* qsc   = (ushort*)(smem + OFF_PQ + 9216) + wave * 256;       // wave-private q 16x16
    ushort* biasl = (ushort*)(smem + OFF_BIAS);

    // preload per-lane biases (coalesced, overlaps everything below)
    float bqr[6], bkr[6], bvr[6], bor[6];
    #pragma unroll
    for (int h = 0; h < 6; ++h) {
        bqr[h] = bq[h * 16 + l15]; bkr[h] = bk[h * 16 + l15];
        bvr[h] = bv[h * 16 + l15]; bor[h] = bo[h * 16 + l15];
    }

    // staging decomposition: p = tid + t*256 over 768 (c,i) rows; c = p%96, i = p/96
    int pc[3], pi[3];
    #pragma unroll
    for (int t = 0; t < 3; ++t) { int p = tid + t * 256; pc[t] = p % 96; pi[t] = p / 96; }

    // ---- issue kv half0 loads ----
    const float* xkvb = xkv + (size_t)b * 192 * 65536;
    float4 pf[3][2];
    #pragma unroll
    for (int t = 0; t < 3; ++t) {
        const float* g = xkvb + (size_t)pc[t] * 65536 + (h0 + pi[t]) * 256 + w0;
        pf[t][0] = *(const float4*)g; pf[t][1] = *(const float4*)(g + 4);
    }
    // stage bias table (from ws, L2-hot) meanwhile
    for (int i = tid; i < 1350; i += 256) biasl[i] = ws[WS_BIAS + i];

    // ---- write kv half0 to A ----
    #pragma unroll
    for (int t = 0; t < 3; ++t) {
        int base = (pi[t] * 8) * STR_A + pc[t];
        A[base]             = f2bf(pf[t][0].x); A[base + STR_A]     = f2bf(pf[t][0].y);
        A[base + 2 * STR_A] = f2bf(pf[t][0].z); A[base + 3 * STR_A] = f2bf(pf[t][0].w);
        A[base + 4 * STR_A] = f2bf(pf[t][1].x); A[base + 5 * STR_A] = f2bf(pf[t][1].y);
        A[base + 6 * STR_A] = f2bf(pf[t][1].z); A[base + 7 * STR_A] = f2bf(pf[t][1].w);
    }
    __syncthreads();

    // ---- issue kv half1 loads (overlap half0 compute) ----
    float4 pg[3][2];
    #pragma unroll
    for (int t = 0; t < 3; ++t) {
        const float* g = xkvb + (size_t)(96 + pc[t]) * 65536 + (h0 + pi[t]) * 256 + w0;
        pg[t][0] = *(const float4*)g; pg[t][1] = *(const float4*)(g + 4);
    }

    // ---- kv half0 MFMAs ----
    f32x4 accK[6], accV[6];
    #pragma unroll
    for (int n = 0; n < 6; ++n) { accK[n] = {}; accV[n] = {}; }
    const int arow = (mt * 16 + l15) * STR_A + quad * 8;
    #pragma unroll
    for (int kt = 0; kt < 3; ++kt) {
        short8 a = *(const short8*)(A + arow + kt * 32);
        #pragma unroll
        for (int nt = 0; nt < 6; ++nt) {
            short8 bk8 = *(const short8*)(ws + WS_WKT + (((kt * 6) + nt) * 64 + lane) * 8);
            accK[nt] = MFMA(a, bk8, accK[nt]);
            short8 bv8 = *(const short8*)(ws + WS_WVT + (((kt * 6) + nt) * 64 + lane) * 8);
            accV[nt] = MFMA(a, bv8, accV[nt]);
        }
    }
    __syncthreads();   // all half0 reads done before restage

    // ---- write kv half1 to A ----
    #pragma unroll
    for (int t = 0; t < 3; ++t) {
        int base = (pi[t] * 8) * STR_A + pc[t];
        A[base]             = f2bf(pg[t][0].x); A[base + STR_A]     = f2bf(pg[t][0].y);
        A[base + 2 * STR_A] = f2bf(pg[t][0].z); A[base + 3 * STR_A] = f2bf(pg[t][0].w);
        A[base + 4 * STR_A] = f2bf(pg[t][1].x); A[base + 5 * STR_A] = f2bf(pg[t][1].y);
        A[base + 6 * STR_A] = f2bf(pg[t][1].z); A[base + 7 * STR_A] = f2bf(pg[t][1].w);
    }
    __syncthreads();

    // ---- issue A_q loads (overlap half1 compute) ----
    const float* xqb = xq + (size_t)b * 96 * 65536;
    #pragma unroll
    for (int t = 0; t < 3; ++t) {
        const float* g = xqb + (size_t)pc[t] * 65536 + (h0 + pi[t]) * 256 + w0;
        pf[t][0] = *(const float4*)g; pf[t][1] = *(const float4*)(g + 4);
    }

    // ---- kv half1 MFMAs ----
    #pragma unroll
    for (int kt = 0; kt < 3; ++kt) {
        short8 a = *(const short8*)(A + arow + kt * 32);
        #pragma unroll
        for (int nt = 0; nt < 6; ++nt) {
            short8 bk8 = *(const short8*)(ws + WS_WKT + ((((3 + kt) * 6) + nt) * 64 + lane) * 8);
            accK[nt] = MFMA(a, bk8, accK[nt]);
            short8 bv8 = *(const short8*)(ws + WS_WVT + ((((3 + kt) * 6) + nt) * 64 + lane) * 8);
            accV[nt] = MFMA(a, bv8, accV[nt]);
        }
    }
    // write k16 [h][tok][d] and vt [h][d][tok] (own-wave token rows)
    #pragma unroll
    for (int nt = 0; nt < 6; ++nt) {
        ushort* dk = k16 + nt * (64 * 16) + (mt * 16 + quad * 4) * 16 + l15;
        ushort* dv = vt + nt * (16 * STR_VT) + l15 * STR_VT + (mt * 16 + quad * 4);
        #pragma unroll
        for (int r = 0; r < 4; ++r) {
            dk[r * 16] = f2bf(accK[nt][r] + bkr[nt]);
            dv[r]      = f2bf(accV[nt][r] + bvr[nt]);
        }
    }
    __syncthreads();   // A free (all half1 reads done) + k16/vt not yet needed

    // ---- write A_q ----
    #pragma unroll
    for (int t = 0; t < 3; ++t) {
        int base = (pi[t] * 8) * STR_A + pc[t];
        A[base]             = f2bf(pf[t][0].x); A[base + STR_A]     = f2bf(pf[t][0].y);
        A[base + 2 * STR_A] = f2bf(pf[t][0].z); A[base + 3 * STR_A] = f2bf(pf[t][0].w);
        A[base + 4 * STR_A] = f2bf(pf[t][1].x); A[base + 5 * STR_A] = f2bf(pf[t][1].y);
        A[base + 6 * STR_A] = f2bf(pf[t][1].z); A[base + 7 * STR_A] = f2bf(pf[t][1].w);
    }
    __syncthreads();   // A_q + k16 + vt all visible

    // ---- precompute rel-bias indices (head-independent) ----
    const int qtok0 = mt * 16 + quad * 4;
    int bidx[4][4];
    #pragma unroll
    for (int nt = 0; nt < 4; ++nt) {
        int kt2 = nt * 16 + l15, i2 = kt2 >> 3, j2 = kt2 & 7;
        #pragma unroll
        for (int r = 0; r < 4; ++r) {
            int qt = qtok0 + r, i1 = qt >> 3, j1 = qt & 7;
            bidx[nt][r] = ((i1 - i2 + 7) * 15 + (j1 - j2 + 7)) * 6;
        }
    }

    // ---- per-head: q-proj -> S = q k^T (+bias) -> softmax -> P v ----
    f32x4 accO[6];
    short8 zero8 = {};
    for (int h = 0; h < 6; ++h) {
        // q projection for this head (wave-private)
        f32x4 qa = {};
        #pragma unroll
        for (int kt = 0; kt < 3; ++kt) {
            short8 a  = *(const short8*)(A + arow + kt * 32);
            short8 bb = *(const short8*)(ws + WS_WQT + ((h * 3 + kt) * 64 + lane) * 8);
            qa = MFMA(a, bb, qa);
        }
        #pragma unroll
        for (int r = 0; r < 4; ++r)
            qsc[(quad * 4 + r) * 16 + l15] = f2bf((qa[r] + bqr[h]) * 0.25f);  // scale=hd^-0.5=2^-2

        short8 aq = zero8;
        if (quad < 2) aq = *(const short8*)(qsc + l15 * 16 + quad * 8);
        f32x4 s[4];
        #pragma unroll
        for (int nt = 0; nt < 4; ++nt) {
            short8 bk8 = zero8;
            if (quad < 2) bk8 = *(const short8*)(k16 + h * (64 * 16) + (nt * 16 + l15) * 16 + quad * 8);
            f32x4 z = {};
            s[nt] = MFMA(aq, bk8, z);
        }
        #pragma unroll
        for (int nt = 0; nt < 4; ++nt)
            #pragma unroll
            for (int r = 0; r < 4; ++r)
                s[nt][r] += bf2f(biasl[bidx[nt][r] + h]);
        // row softmax within 16-lane quad group
        float pr[4][4];
        #pragma unroll
        for (int r = 0; r < 4; ++r) {
            float m = fmaxf(fmaxf(s[0][r], s[1][r]), fmaxf(s[2][r], s[3][r]));
            m = fmaxf(m, __shfl_xor(m, 1)); m = fmaxf(m, __shfl_xor(m, 2));
            m = fmaxf(m, __shfl_xor(m, 4)); m = fmaxf(m, __shfl_xor(m, 8));
            float l = 0.f;
            #pragma unroll
            for (int nt = 0; nt < 4; ++nt) { pr[nt][r] = __expf(s[nt][r] - m); l += pr[nt][r]; }
            l += __shfl_xor(l, 1); l += __shfl_xor(l, 2);
            l += __shfl_xor(l, 4); l += __shfl_xor(l, 8);
            float inv = 1.0f / l;
            #pragma unroll
            for (int nt = 0; nt < 4; ++nt) pr[nt][r] *= inv;
        }
        // C-layout -> A-layout via wave-private LDS
        #pragma unroll
        for (int nt = 0; nt < 4; ++nt)
            #pragma unroll
            for (int r = 0; r < 4; ++r)
                ps[(quad * 4 + r) * P_STRIDE + nt * 16 + l15] = f2bf(pr[nt][r]);
        f32x4 o = {};
        #pragma unroll
        for (int k2 = 0; k2 < 2; ++k2) {
            short8 ap  = *(const short8*)(ps + l15 * P_STRIDE + k2 * 32 + quad * 8);
            short8 bv8 = *(const short8*)(vt + h * (16 * STR_VT) + l15 * STR_VT + k2 * 32 + quad * 8);
            o = MFMA(ap, bv8, o);
        }
        accO[h] = o;
    }
    __syncthreads();   // safety before A-region reuse as obuf

    // ---- concat heads into obuf (own-wave rows only) ----
    ushort* obuf = A;
    #pragma unroll
    for (int h = 0; h < 6; ++h)
        #pragma unroll
        for (int r = 0; r < 4; ++r)
            obuf[(mt * 16 + quad * 4 + r) * STR_A + h * 16 + l15] = f2bf(accO[h][r]);

    // ---- out projection + float4 store (own-wave rows; no barrier needed) ----
    {
        int t0 = mt * 16 + quad * 4;
        int i = t0 >> 3, j0 = t0 & 7;
        #pragma unroll
        for (int nt = 0; nt < 6; ++nt) {
            f32x4 acc = {};
            #pragma unroll
            for (int kt = 0; kt < 3; ++kt) {
                short8 a  = *(const short8*)(obuf + arow + kt * 32);
                short8 bb = *(const short8*)(ws + WS_WOT + ((nt * 3 + kt) * 64 + lane) * 8);
                acc = MFMA(a, bb, acc);
            }
            int cout = nt * 16 + l15;
            float4 v4 = make_float4(acc[0] + bor[nt], acc[1] + bor[nt], acc[2] + bor[nt], acc[3] + bor[nt]);
            float* dst = out + (size_t)(b * 96 + cout) * 65536 + (h0 + i) * 256 + w0 + j0;
            *(float4*)dst = v4;
        }
    }
}

extern "C" void kernel_launch(void* const* d_in, const int* in_sizes, int n_in,
                              void* d_out, int out_size, void* d_ws, size_t ws_size,
                              hipStream_t stream) {
    const float* xq   = (const float*)d_in[0];
    const float* xkv  = (const float*)d_in[1];
    const float* Wq   = (const float*)d_in[2];
    const float* bq   = (const float*)d_in[3];
    const float* Wk   = (const float*)d_in[4];
    const float* bk   = (const float*)d_in[5];
    const float* Wv   = (const float*)d_in[6];
    const float* bv   = (const float*)d_in[7];
    const float* btab = (const float*)d_in[8];
    const float* Wo   = (const float*)d_in[9];
    const float* bo   = (const float*)d_in[10];
    ushort* ws = (ushort*)d_ws;
    float* out = (float*)d_out;

    hipLaunchKernelGGL(prep_weights, dim3((WS_TOTAL + 255) / 256), dim3(256), 0, stream,
                       Wq, Wk, Wv, Wo, btab, ws);
    hipLaunchKernelGGL(swin_attn, dim3(4096), dim3(256), 0, stream,
                       xq, xkv, bq, bk, bv, bo, ws, out);
}